// Round 1
// 514.501 us; speedup vs baseline: 1.1696x; 1.1696x over previous
//
#include <hip/hip_runtime.h>

typedef unsigned int u32;
typedef unsigned short u16;
typedef __bf16 bf16x8 __attribute__((ext_vector_type(8)));
typedef float f32x4 __attribute__((ext_vector_type(4)));

#define M_TOT 8192
#define N_TOT 4096
#define K_TOT 4096
#define RANK 16

#define BM 256
#define BN 256
#define BK 64
#define NT (K_TOT / BK)

__constant__ float NF4_TAB[16] = {
    -1.0f, -0.6961928009986877f, -0.5250730514526367f, -0.39491748809814453f,
    -0.28444138169288635f, -0.18477343022823334f, -0.09105003625154495f, 0.0f,
    0.07958029955625534f, 0.16093020141124725f, 0.24611230194568634f,
    0.33791524171829224f, 0.44070982933044434f, 0.5626170039176941f,
    0.7229568362236023f, 1.0f};

__device__ __forceinline__ u16 f2bf(float f) {
  u32 u = __builtin_bit_cast(u32, f);
  return (u16)((u + 0x7FFFu + ((u >> 16) & 1u)) >> 16);  // RNE
}

__device__ __forceinline__ void async_copy16(const u16* g, u16* l) {
  __builtin_amdgcn_global_load_lds(
      (const __attribute__((address_space(1))) u32*)g,
      (__attribute__((address_space(3))) u32*)l, 16, 0, 0);
}

// ---------------- x fp32 -> bf16 (8 elems/thread) ----------------
__global__ __launch_bounds__(256) void cvt_kernel(const float* __restrict__ x,
                                                  u16* __restrict__ xb) {
  int t = blockIdx.x * 256 + threadIdx.x;
  const float4* xv = (const float4*)x;
  float4 v0 = xv[2 * t], v1 = xv[2 * t + 1];
  uint4 o;
  o.x = (u32)f2bf(v0.x) | ((u32)f2bf(v0.y) << 16);
  o.y = (u32)f2bf(v0.z) | ((u32)f2bf(v0.w) << 16);
  o.z = (u32)f2bf(v1.x) | ((u32)f2bf(v1.y) << 16);
  o.w = (u32)f2bf(v1.z) | ((u32)f2bf(v1.w) << 16);
  ((uint4*)xb)[t] = o;
}

// ---------------- NF4 dequant + LoRA fold ----------------
__global__ __launch_bounds__(256) void dequant_kernel(
    const int* __restrict__ wq, const float* __restrict__ scales,
    const float* __restrict__ Aw, const float* __restrict__ Bw,
    u16* __restrict__ Wb) {
  __shared__ float Bs[16 * RANK];
  int t = threadIdx.x;
  int o0 = blockIdx.y * 16;
  int tabi = __builtin_bit_cast(int, NF4_TAB[t & 15]);
  Bs[t] = Bw[o0 * RANK + t];
  __syncthreads();

  int i0 = blockIdx.x * 1024 + t * 4;
  float a[RANK][4];
#pragma unroll
  for (int r = 0; r < RANK; ++r) {
    float4 v = *(const float4*)(Aw + r * K_TOT + i0);
    a[r][0] = v.x; a[r][1] = v.y; a[r][2] = v.z; a[r][3] = v.w;
  }
#pragma unroll
  for (int j = 0; j < 16; ++j) {
    int o = o0 + j;
    int4 q = *(const int4*)(wq + (size_t)o * K_TOT + i0);
    float s = scales[o * (K_TOT / 64) + (i0 >> 6)];
    float d0 = 0.f, d1 = 0.f, d2 = 0.f, d3 = 0.f;
#pragma unroll
    for (int r = 0; r < RANK; ++r) {
      float b = Bs[j * RANK + r];
      d0 += b * a[r][0]; d1 += b * a[r][1];
      d2 += b * a[r][2]; d3 += b * a[r][3];
    }
    float t0 = __builtin_bit_cast(float, __builtin_amdgcn_ds_bpermute((q.x & 15) << 2, tabi));
    float t1 = __builtin_bit_cast(float, __builtin_amdgcn_ds_bpermute((q.y & 15) << 2, tabi));
    float t2 = __builtin_bit_cast(float, __builtin_amdgcn_ds_bpermute((q.z & 15) << 2, tabi));
    float t3 = __builtin_bit_cast(float, __builtin_amdgcn_ds_bpermute((q.w & 15) << 2, tabi));
    float w0 = t0 * s + 2.0f * d0;
    float w1 = t1 * s + 2.0f * d1;
    float w2 = t2 * s + 2.0f * d2;
    float w3 = t3 * s + 2.0f * d3;
    uint2 ov;
    ov.x = (u32)f2bf(w0) | ((u32)f2bf(w1) << 16);
    ov.y = (u32)f2bf(w2) | ((u32)f2bf(w3) << 16);
    *(uint2*)(Wb + (size_t)o * K_TOT + i0) = ov;
  }
}

// ---------------- bf16 GEMM: C[M,N] = A[M,K] * B[N,K]^T ----------------
// 256x256 tile, BK=64, 8 waves (2M x 4N), 128 KiB double-buffered LDS.
// 4-phase K-step, counted vmcnt (never 0 in main loop), setprio around MFMA.
// XOR swizzle g^(row&7): staged via pre-swizzled global source, linear LDS dest.
#define STAGE_A(buf, k0, i) \
  async_copy16(gA + (size_t)(i) * 64 * K_TOT + (k0), &sh[buf][0][(i) * 4096 + tid * 8])
#define STAGE_B(buf, k0, i) \
  async_copy16(gB + (size_t)(i) * 64 * K_TOT + (k0), &sh[buf][1][(i) * 4096 + tid * 8])

#define LOAD_A(mh)                                              \
  do {                                                          \
    const u16* p_ = sA + (wm * 128 + (mh) * 64 + m) * 64;       \
    _Pragma("unroll") for (int i_ = 0; i_ < 4; ++i_) {          \
      af[i_][0] = *(const bf16x8*)(p_ + i_ * 16 * 64 + off0);   \
      af[i_][1] = *(const bf16x8*)(p_ + i_ * 16 * 64 + off1);   \
    }                                                           \
  } while (0)

#define LOAD_B(nh)                                              \
  do {                                                          \
    const u16* p_ = sB + (wn * 64 + (nh) * 32 + m) * 64;        \
    _Pragma("unroll") for (int j_ = 0; j_ < 2; ++j_) {          \
      bfr[j_][0] = *(const bf16x8*)(p_ + j_ * 16 * 64 + off0);  \
      bfr[j_][1] = *(const bf16x8*)(p_ + j_ * 16 * 64 + off1);  \
    }                                                           \
  } while (0)

#define PHASE_TAIL(mh, nh)                                                  \
  do {                                                                      \
    __builtin_amdgcn_s_barrier();                                           \
    asm volatile("s_waitcnt lgkmcnt(0)" ::: "memory");                      \
    __builtin_amdgcn_sched_barrier(0);                                      \
    __builtin_amdgcn_s_setprio(1);                                          \
    _Pragma("unroll") for (int kk_ = 0; kk_ < 2; ++kk_)                     \
    _Pragma("unroll") for (int i_ = 0; i_ < 4; ++i_)                        \
    _Pragma("unroll") for (int j_ = 0; j_ < 2; ++j_)                        \
      acc[(mh) * 4 + i_][(nh) * 2 + j_] =                                   \
          __builtin_amdgcn_mfma_f32_16x16x32_bf16(                          \
              af[i_][kk_], bfr[j_][kk_], acc[(mh) * 4 + i_][(nh) * 2 + j_], \
              0, 0, 0);                                                     \
    __builtin_amdgcn_s_setprio(0);                                          \
    __builtin_amdgcn_s_barrier();                                           \
  } while (0)

__global__ __launch_bounds__(512, 2) void gemm_kernel(const u16* __restrict__ A,
                                                      const u16* __restrict__ B,
                                                      float* __restrict__ C) {
  __shared__ __align__(16) u16 sh[2][2][BM * BK];  // 128 KiB

  int tid = threadIdx.x;
  int lane = tid & 63, wave = tid >> 6;
  int wm = wave >> 2, wn = wave & 3;  // 2 x 4 wave grid, 128x64 out per wave

  // XCD-aware swizzle: 512 wgs, 512 % 8 == 0 -> simple form is bijective.
  int bid = blockIdx.y * gridDim.x + blockIdx.x;
  int swz = (bid & 7) * 64 + (bid >> 3);
  int bm = swz >> 4, bn = swz & 15;

  // Staging: instr i covers rows i*64..i*64+63; lane granule tid&7 (linear
  // dest), source granule pre-swizzled by row&7 so reads can un-swizzle.
  int srow = tid >> 3;
  int sg = (tid & 7) ^ (srow & 7);
  const u16* gA = A + (size_t)(bm * BM + srow) * K_TOT + sg * 8;
  const u16* gB = B + (size_t)(bn * BN + srow) * K_TOT + sg * 8;

  // Fragment addressing (verified layout): lane = q*16+m holds k=8q..8q+8 of
  // row m; granule g stored at g^(row&7), row&7 == m&7.
  int m = lane & 15, q = lane >> 4;
  int x7 = m & 7;
  int off0 = (q ^ x7) << 3;
  int off1 = ((q + 4) ^ x7) << 3;

  f32x4 acc[8][4] = {};
  bf16x8 af[4][2], bfr[2][2];

  // Prologue: stage tile 0 into buf 0 (8 loads).
#pragma unroll
  for (int i = 0; i < 4; ++i) {
    STAGE_A(0, 0, i);
    STAGE_B(0, 0, i);
  }

  for (int t = 0; t < NT - 1; ++t) {
    int cur = t & 1, nxt = cur ^ 1;
    int k1 = (t + 1) * BK;
    const u16* sA = sh[cur][0];
    const u16* sB = sh[cur][1];

    // Head: issue next tile's A loads, then drain THIS tile's 8 loads only
    // (the 4 just issued stay in flight across the barrier).
#pragma unroll
    for (int i = 0; i < 4; ++i) STAGE_A(nxt, k1, i);
    asm volatile("s_waitcnt vmcnt(4)" ::: "memory");
    __builtin_amdgcn_s_barrier();

    // Phase 0: quadrant (0,0) — 12 ds_read, stage B half 0
    LOAD_A(0);
    LOAD_B(0);
    STAGE_B(nxt, k1, 0);
    STAGE_B(nxt, k1, 1);
    PHASE_TAIL(0, 0);

    // Phase 1: quadrant (0,1) — A reused, stage B half 1
    LOAD_B(1);
    STAGE_B(nxt, k1, 2);
    STAGE_B(nxt, k1, 3);
    PHASE_TAIL(0, 1);

    // Phase 2: quadrant (1,1) — B reused
    LOAD_A(1);
    PHASE_TAIL(1, 1);

    // Phase 3: quadrant (1,0)
    LOAD_B(0);
    PHASE_TAIL(1, 0);
  }

  // Epilogue tile NT-1: no staging, full drain allowed here.
  {
    const u16* sA = sh[(NT - 1) & 1][0];
    const u16* sB = sh[(NT - 1) & 1][1];
    asm volatile("s_waitcnt vmcnt(0)" ::: "memory");
    __builtin_amdgcn_s_barrier();
    LOAD_A(0);
    LOAD_B(0);
    PHASE_TAIL(0, 0);
    LOAD_B(1);
    PHASE_TAIL(0, 1);
    LOAD_A(1);
    PHASE_TAIL(1, 1);
    LOAD_B(0);
    PHASE_TAIL(1, 0);
  }

  // C/D layout: col = lane&15, row = (lane>>4)*4 + reg
  int r0 = bm * BM + wm * 128 + (q << 2);
  int c0 = bn * BN + wn * 64 + m;
#pragma unroll
  for (int i = 0; i < 8; ++i)
#pragma unroll
    for (int j = 0; j < 4; ++j)
#pragma unroll
      for (int p = 0; p < 4; ++p)
        C[(size_t)(r0 + i * 16 + p) * N_TOT + (c0 + j * 16)] = acc[i][j][p];
}

extern "C" void kernel_launch(void* const* d_in, const int* in_sizes, int n_in,
                              void* d_out, int out_size, void* d_ws, size_t ws_size,
                              hipStream_t stream) {
  const float* x = (const float*)d_in[0];       // [4,2048,4096] fp32
  const int* wq = (const int*)d_in[1];          // [4096,4096] int32
  const float* scales = (const float*)d_in[2];  // [4096,64] fp32
  const float* Aw = (const float*)d_in[3];      // [16,4096] fp32
  const float* Bw = (const float*)d_in[4];      // [4096,16] fp32
  float* out = (float*)d_out;                   // [8192,4096] fp32

  u16* xb = (u16*)d_ws;                                       // 67,108,864 B
  u16* Wb = (u16*)((char*)d_ws + (size_t)M_TOT * K_TOT * 2);  // 33,554,432 B

  cvt_kernel<<<(M_TOT * K_TOT) / (256 * 8), 256, 0, stream>>>(x, xb);
  dequant_kernel<<<dim3(K_TOT / 1024, N_TOT / 16), 256, 0, stream>>>(wq, scales, Aw, Bw, Wb);
  gemm_kernel<<<dim3(N_TOT / BN, M_TOT / BM), 512, 0, stream>>>(xb, Wb, out);
}

// Round 2
// 514.217 us; speedup vs baseline: 1.1702x; 1.0006x over previous
//
#include <hip/hip_runtime.h>

typedef unsigned int u32;
typedef unsigned short u16;
typedef __bf16 bf16x8 __attribute__((ext_vector_type(8)));
typedef float f32x4 __attribute__((ext_vector_type(4)));

#define M_TOT 8192
#define N_TOT 4096
#define K_TOT 4096
#define RANK 16

#define BM 256
#define BN 256
#define BK 64
#define NT (K_TOT / BK)

#define CVT_BLOCKS 16384  // (M_TOT*K_TOT)/(256*8)

__constant__ float NF4_TAB[16] = {
    -1.0f, -0.6961928009986877f, -0.5250730514526367f, -0.39491748809814453f,
    -0.28444138169288635f, -0.18477343022823334f, -0.09105003625154495f, 0.0f,
    0.07958029955625534f, 0.16093020141124725f, 0.24611230194568634f,
    0.33791524171829224f, 0.44070982933044434f, 0.5626170039176941f,
    0.7229568362236023f, 1.0f};

__device__ __forceinline__ u16 f2bf(float f) {
  u32 u = __builtin_bit_cast(u32, f);
  return (u16)((u + 0x7FFFu + ((u >> 16) & 1u)) >> 16);  // RNE
}

__device__ __forceinline__ void async_copy16(const u16* g, u16* l) {
  __builtin_amdgcn_global_load_lds(
      (const __attribute__((address_space(1))) u32*)g,
      (__attribute__((address_space(3))) u32*)l, 16, 0, 0);
}

// ---------------- fused prep: x fp32->bf16  +  NF4 dequant + LoRA fold ----
// Independent jobs split by blockIdx.x; fusing saves a launch and overlaps
// the small dequant grid with cvt.
__global__ __launch_bounds__(256) void prep_kernel(
    const float* __restrict__ x, u16* __restrict__ xb,
    const int* __restrict__ wq, const float* __restrict__ scales,
    const float* __restrict__ Aw, const float* __restrict__ Bw,
    u16* __restrict__ Wb) {
  if (blockIdx.x < CVT_BLOCKS) {
    int t = blockIdx.x * 256 + threadIdx.x;
    const float4* xv = (const float4*)x;
    float4 v0 = xv[2 * t], v1 = xv[2 * t + 1];
    uint4 o;
    o.x = (u32)f2bf(v0.x) | ((u32)f2bf(v0.y) << 16);
    o.y = (u32)f2bf(v0.z) | ((u32)f2bf(v0.w) << 16);
    o.z = (u32)f2bf(v1.x) | ((u32)f2bf(v1.y) << 16);
    o.w = (u32)f2bf(v1.z) | ((u32)f2bf(v1.w) << 16);
    ((uint4*)xb)[t] = o;
    return;
  }
  int db = blockIdx.x - CVT_BLOCKS;
  int bx = db & 3, by = db >> 2;

  __shared__ float Bs[16 * RANK];
  int t = threadIdx.x;
  int o0 = by * 16;
  int tabi = __builtin_bit_cast(int, NF4_TAB[t & 15]);
  Bs[t] = Bw[o0 * RANK + t];
  __syncthreads();

  int i0 = bx * 1024 + t * 4;
  float a[RANK][4];
#pragma unroll
  for (int r = 0; r < RANK; ++r) {
    float4 v = *(const float4*)(Aw + r * K_TOT + i0);
    a[r][0] = v.x; a[r][1] = v.y; a[r][2] = v.z; a[r][3] = v.w;
  }
#pragma unroll
  for (int j = 0; j < 16; ++j) {
    int o = o0 + j;
    int4 q = *(const int4*)(wq + (size_t)o * K_TOT + i0);
    float s = scales[o * (K_TOT / 64) + (i0 >> 6)];
    float d0 = 0.f, d1 = 0.f, d2 = 0.f, d3 = 0.f;
#pragma unroll
    for (int r = 0; r < RANK; ++r) {
      float b = Bs[j * RANK + r];
      d0 += b * a[r][0]; d1 += b * a[r][1];
      d2 += b * a[r][2]; d3 += b * a[r][3];
    }
    float t0 = __builtin_bit_cast(float, __builtin_amdgcn_ds_bpermute((q.x & 15) << 2, tabi));
    float t1 = __builtin_bit_cast(float, __builtin_amdgcn_ds_bpermute((q.y & 15) << 2, tabi));
    float t2 = __builtin_bit_cast(float, __builtin_amdgcn_ds_bpermute((q.z & 15) << 2, tabi));
    float t3 = __builtin_bit_cast(float, __builtin_amdgcn_ds_bpermute((q.w & 15) << 2, tabi));
    float w0 = t0 * s + 2.0f * d0;
    float w1 = t1 * s + 2.0f * d1;
    float w2 = t2 * s + 2.0f * d2;
    float w3 = t3 * s + 2.0f * d3;
    uint2 ov;
    ov.x = (u32)f2bf(w0) | ((u32)f2bf(w1) << 16);
    ov.y = (u32)f2bf(w2) | ((u32)f2bf(w3) << 16);
    *(uint2*)(Wb + (size_t)o * K_TOT + i0) = ov;
  }
}

// ---------------- bf16 GEMM: C[M,N] = A[M,K] * B[N,K]^T ----------------
// 256x256 tile, BK=64, 8 waves (2M x 4N), 128 KiB double-buffered LDS.
// 4-phase K-step, counted vmcnt, setprio around MFMA. Both B halves stay
// register-resident (bfr[4]) so phase 3 issues ZERO ds_reads:
//   p0: read A0(8)+B0(4) -> mfma(0,0)   p1: read B1(4) -> mfma(0,1)
//   p2: read A1(8)       -> mfma(1,1)   p3: no reads   -> mfma(1,0)
// LDS fragment traffic: 24 KB/wave/K-tile (was 28).
#define STAGE_A(buf, k0, i) \
  async_copy16(gA + (size_t)(i) * 64 * K_TOT + (k0), &sh[buf][0][(i) * 4096 + tid * 8])
#define STAGE_B(buf, k0, i) \
  async_copy16(gB + (size_t)(i) * 64 * K_TOT + (k0), &sh[buf][1][(i) * 4096 + tid * 8])

#define LOAD_A(mh)                                              \
  do {                                                          \
    const u16* p_ = sA + (wm * 128 + (mh) * 64 + m) * 64;       \
    _Pragma("unroll") for (int i_ = 0; i_ < 4; ++i_) {          \
      af[i_][0] = *(const bf16x8*)(p_ + i_ * 16 * 64 + off0);   \
      af[i_][1] = *(const bf16x8*)(p_ + i_ * 16 * 64 + off1);   \
    }                                                           \
  } while (0)

#define LOAD_B(nh)                                                        \
  do {                                                                    \
    const u16* p_ = sB + (wn * 64 + (nh) * 32 + m) * 64;                  \
    _Pragma("unroll") for (int j_ = 0; j_ < 2; ++j_) {                    \
      bfr[(nh) * 2 + j_][0] = *(const bf16x8*)(p_ + j_ * 16 * 64 + off0); \
      bfr[(nh) * 2 + j_][1] = *(const bf16x8*)(p_ + j_ * 16 * 64 + off1); \
    }                                                                     \
  } while (0)

#define PHASE_TAIL(mh, nh)                                                  \
  do {                                                                      \
    __builtin_amdgcn_s_barrier();                                           \
    asm volatile("s_waitcnt lgkmcnt(0)" ::: "memory");                      \
    __builtin_amdgcn_sched_barrier(0);                                      \
    __builtin_amdgcn_s_setprio(1);                                          \
    _Pragma("unroll") for (int kk_ = 0; kk_ < 2; ++kk_)                     \
    _Pragma("unroll") for (int i_ = 0; i_ < 4; ++i_)                        \
    _Pragma("unroll") for (int j_ = 0; j_ < 2; ++j_)                        \
      acc[(mh) * 4 + i_][(nh) * 2 + j_] =                                   \
          __builtin_amdgcn_mfma_f32_16x16x32_bf16(                          \
              af[i_][kk_], bfr[(nh) * 2 + j_][kk_],                         \
              acc[(mh) * 4 + i_][(nh) * 2 + j_], 0, 0, 0);                  \
    __builtin_amdgcn_s_setprio(0);                                          \
    __builtin_amdgcn_s_barrier();                                           \
  } while (0)

__global__ __launch_bounds__(512, 2) void gemm_kernel(const u16* __restrict__ A,
                                                      const u16* __restrict__ B,
                                                      float* __restrict__ C) {
  __shared__ __align__(16) u16 sh[2][2][BM * BK];  // 128 KiB

  int tid = threadIdx.x;
  int lane = tid & 63, wave = tid >> 6;
  int wm = wave >> 2, wn = wave & 3;  // 2 x 4 wave grid, 128x64 out per wave

  // XCD-aware swizzle: 512 wgs, 512 % 8 == 0 -> simple form is bijective.
  int bid = blockIdx.y * gridDim.x + blockIdx.x;
  int swz = (bid & 7) * 64 + (bid >> 3);
  int bm = swz >> 4, bn = swz & 15;

  // Staging: instr i covers rows i*64..i*64+63; lane granule tid&7 (linear
  // dest), source granule pre-swizzled by row&7 so reads can un-swizzle.
  int srow = tid >> 3;
  int sg = (tid & 7) ^ (srow & 7);
  const u16* gA = A + (size_t)(bm * BM + srow) * K_TOT + sg * 8;
  const u16* gB = B + (size_t)(bn * BN + srow) * K_TOT + sg * 8;

  // Fragment addressing: lane = q*16+m holds k=8q..8q+8 of row m; granule g
  // stored at g^(row&7), row&7 == m&7.
  int m = lane & 15, q = lane >> 4;
  int x7 = m & 7;
  int off0 = (q ^ x7) << 3;
  int off1 = ((q + 4) ^ x7) << 3;

  f32x4 acc[8][4] = {};
  bf16x8 af[4][2], bfr[4][2];

  // Prologue: stage tile 0 into buf 0 (8 loads).
#pragma unroll
  for (int i = 0; i < 4; ++i) {
    STAGE_A(0, 0, i);
    STAGE_B(0, 0, i);
  }

  for (int t = 0; t < NT - 1; ++t) {
    int cur = t & 1, nxt = cur ^ 1;
    int k1 = (t + 1) * BK;
    const u16* sA = sh[cur][0];
    const u16* sB = sh[cur][1];

    // Head: issue next tile's A loads, then drain THIS tile's 8 loads only
    // (the 4 just issued stay in flight across the barrier).
#pragma unroll
    for (int i = 0; i < 4; ++i) STAGE_A(nxt, k1, i);
    asm volatile("s_waitcnt vmcnt(4)" ::: "memory");
    __builtin_amdgcn_s_barrier();

    // Phase 0: quadrant (0,0) — 12 ds_read, stage B half 0
    LOAD_A(0);
    LOAD_B(0);
    STAGE_B(nxt, k1, 0);
    STAGE_B(nxt, k1, 1);
    asm volatile("s_waitcnt lgkmcnt(8)" ::: "memory");
    PHASE_TAIL(0, 0);

    // Phase 1: quadrant (0,1) — A reused, read B half 1, stage B half 1
    LOAD_B(1);
    STAGE_B(nxt, k1, 2);
    STAGE_B(nxt, k1, 3);
    PHASE_TAIL(0, 1);

    // Phase 2: quadrant (1,1) — B1 resident, read A half 1
    LOAD_A(1);
    PHASE_TAIL(1, 1);

    // Phase 3: quadrant (1,0) — everything resident, pure MFMA
    PHASE_TAIL(1, 0);
  }

  // Epilogue tile NT-1: no staging, full drain allowed here.
  {
    const u16* sA = sh[(NT - 1) & 1][0];
    const u16* sB = sh[(NT - 1) & 1][1];
    asm volatile("s_waitcnt vmcnt(0)" ::: "memory");
    __builtin_amdgcn_s_barrier();
    LOAD_A(0);
    LOAD_B(0);
    asm volatile("s_waitcnt lgkmcnt(8)" ::: "memory");
    PHASE_TAIL(0, 0);
    LOAD_B(1);
    PHASE_TAIL(0, 1);
    LOAD_A(1);
    PHASE_TAIL(1, 1);
    PHASE_TAIL(1, 0);
  }

  // C/D layout: col = lane&15, row = (lane>>4)*4 + reg
  int r0 = bm * BM + wm * 128 + (q << 2);
  int c0 = bn * BN + wn * 64 + m;
#pragma unroll
  for (int i = 0; i < 8; ++i)
#pragma unroll
    for (int j = 0; j < 4; ++j)
#pragma unroll
      for (int p = 0; p < 4; ++p)
        C[(size_t)(r0 + i * 16 + p) * N_TOT + (c0 + j * 16)] = acc[i][j][p];
}

extern "C" void kernel_launch(void* const* d_in, const int* in_sizes, int n_in,
                              void* d_out, int out_size, void* d_ws, size_t ws_size,
                              hipStream_t stream) {
  const float* x = (const float*)d_in[0];       // [4,2048,4096] fp32
  const int* wq = (const int*)d_in[1];          // [4096,4096] int32
  const float* scales = (const float*)d_in[2];  // [4096,64] fp32
  const float* Aw = (const float*)d_in[3];      // [16,4096] fp32
  const float* Bw = (const float*)d_in[4];      // [4096,16] fp32
  float* out = (float*)d_out;                   // [8192,4096] fp32

  u16* xb = (u16*)d_ws;                                       // 67,108,864 B
  u16* Wb = (u16*)((char*)d_ws + (size_t)M_TOT * K_TOT * 2);  // 33,554,432 B

  prep_kernel<<<CVT_BLOCKS + (K_TOT / 1024) * (N_TOT / 16), 256, 0, stream>>>(
      x, xb, wq, scales, Aw, Bw, Wb);
  gemm_kernel<<<dim3(N_TOT / BN, M_TOT / BM), 512, 0, stream>>>(xb, Wb, out);
}

// Round 3
// 483.878 us; speedup vs baseline: 1.2436x; 1.0627x over previous
//
#include <hip/hip_runtime.h>

typedef unsigned int u32;
typedef unsigned short u16;
typedef __bf16 bf16x8 __attribute__((ext_vector_type(8)));
typedef float f32x4 __attribute__((ext_vector_type(4)));

#define M_TOT 8192
#define N_TOT 4096
#define K_TOT 4096
#define RANK 16

#define BM 256
#define BN 256
#define BK 64
#define NT (K_TOT / BK)

#define DQ_BLOCKS 1024   // (K_TOT/1024)*(N_TOT/16)
#define CVT_BLOCKS 16384  // (M_TOT*K_TOT)/(256*8)

__constant__ float NF4_TAB[16] = {
    -1.0f, -0.6961928009986877f, -0.5250730514526367f, -0.39491748809814453f,
    -0.28444138169288635f, -0.18477343022823334f, -0.09105003625154495f, 0.0f,
    0.07958029955625534f, 0.16093020141124725f, 0.24611230194568634f,
    0.33791524171829224f, 0.44070982933044434f, 0.5626170039176941f,
    0.7229568362236023f, 1.0f};

__device__ __forceinline__ u16 f2bf(float f) {
  u32 u = __builtin_bit_cast(u32, f);
  return (u16)((u + 0x7FFFu + ((u >> 16) & 1u)) >> 16);  // RNE
}

__device__ __forceinline__ void async_copy16(const u16* g, u16* l) {
  __builtin_amdgcn_global_load_lds(
      (const __attribute__((address_space(1))) u32*)g,
      (__attribute__((address_space(3))) u32*)l, 16, 0, 0);
}

// ---------------- fused prep: NF4 dequant + LoRA fold FIRST, then cvt ----
// dequant blocks dispatched first so the small grid overlaps cvt instead of
// trailing it.
__global__ __launch_bounds__(256) void prep_kernel(
    const float* __restrict__ x, u16* __restrict__ xb,
    const int* __restrict__ wq, const float* __restrict__ scales,
    const float* __restrict__ Aw, const float* __restrict__ Bw,
    u16* __restrict__ Wb) {
  if (blockIdx.x >= DQ_BLOCKS) {
    int t = (blockIdx.x - DQ_BLOCKS) * 256 + threadIdx.x;
    const float4* xv = (const float4*)x;
    float4 v0 = xv[2 * t], v1 = xv[2 * t + 1];
    uint4 o;
    o.x = (u32)f2bf(v0.x) | ((u32)f2bf(v0.y) << 16);
    o.y = (u32)f2bf(v0.z) | ((u32)f2bf(v0.w) << 16);
    o.z = (u32)f2bf(v1.x) | ((u32)f2bf(v1.y) << 16);
    o.w = (u32)f2bf(v1.z) | ((u32)f2bf(v1.w) << 16);
    ((uint4*)xb)[t] = o;
    return;
  }
  int bx = blockIdx.x & 3, by = blockIdx.x >> 2;

  __shared__ float Bs[16 * RANK];
  int t = threadIdx.x;
  int o0 = by * 16;
  int tabi = __builtin_bit_cast(int, NF4_TAB[t & 15]);
  Bs[t] = Bw[o0 * RANK + t];
  __syncthreads();

  int i0 = bx * 1024 + t * 4;
  float a[RANK][4];
#pragma unroll
  for (int r = 0; r < RANK; ++r) {
    float4 v = *(const float4*)(Aw + r * K_TOT + i0);
    a[r][0] = v.x; a[r][1] = v.y; a[r][2] = v.z; a[r][3] = v.w;
  }
#pragma unroll
  for (int j = 0; j < 16; ++j) {
    int o = o0 + j;
    int4 q = *(const int4*)(wq + (size_t)o * K_TOT + i0);
    float s = scales[o * (K_TOT / 64) + (i0 >> 6)];
    float d0 = 0.f, d1 = 0.f, d2 = 0.f, d3 = 0.f;
#pragma unroll
    for (int r = 0; r < RANK; ++r) {
      float b = Bs[j * RANK + r];
      d0 += b * a[r][0]; d1 += b * a[r][1];
      d2 += b * a[r][2]; d3 += b * a[r][3];
    }
    float t0 = __builtin_bit_cast(float, __builtin_amdgcn_ds_bpermute((q.x & 15) << 2, tabi));
    float t1 = __builtin_bit_cast(float, __builtin_amdgcn_ds_bpermute((q.y & 15) << 2, tabi));
    float t2 = __builtin_bit_cast(float, __builtin_amdgcn_ds_bpermute((q.z & 15) << 2, tabi));
    float t3 = __builtin_bit_cast(float, __builtin_amdgcn_ds_bpermute((q.w & 15) << 2, tabi));
    float w0 = t0 * s + 2.0f * d0;
    float w1 = t1 * s + 2.0f * d1;
    float w2 = t2 * s + 2.0f * d2;
    float w3 = t3 * s + 2.0f * d3;
    uint2 ov;
    ov.x = (u32)f2bf(w0) | ((u32)f2bf(w1) << 16);
    ov.y = (u32)f2bf(w2) | ((u32)f2bf(w3) << 16);
    *(uint2*)(Wb + (size_t)o * K_TOT + i0) = ov;
  }
}

// ---------------- bf16 GEMM: C[M,N] = A[M,K] * B[N,K]^T ----------------
// m201-faithful 8-phase ring: 2 K-tiles per iteration, 2 stage-chunks per
// phase, counted vmcnt(6) only at phases 3/7 (after MFMA), no head block.
// Per phase: {ds_read quadrant | 2 gload_lds} -> barrier -> lgkmcnt(0) ->
// setprio(1) 16 MFMA setprio(0) [vmcnt] -> barrier.
// Write-after-read safety: each chunk staged >=1 phase after its old data's
// last ds_read (issue-after-drain => async write cannot precede the reads).
#define STAGE_A(buf, k0, i) \
  async_copy16(gA + (size_t)(i) * 64 * K_TOT + (k0), &sh[buf][0][(i) * 4096 + tid * 8])
#define STAGE_B(buf, k0, i) \
  async_copy16(gB + (size_t)(i) * 64 * K_TOT + (k0), &sh[buf][1][(i) * 4096 + tid * 8])

#define LOAD_A(mh)                                              \
  do {                                                          \
    const u16* p_ = sA + (wm * 128 + (mh) * 64 + m) * 64;       \
    _Pragma("unroll") for (int i_ = 0; i_ < 4; ++i_) {          \
      af[i_][0] = *(const bf16x8*)(p_ + i_ * 16 * 64 + off0);   \
      af[i_][1] = *(const bf16x8*)(p_ + i_ * 16 * 64 + off1);   \
    }                                                           \
  } while (0)

#define LOAD_B(nh)                                                        \
  do {                                                                    \
    const u16* p_ = sB + (wn * 64 + (nh) * 32 + m) * 64;                  \
    _Pragma("unroll") for (int j_ = 0; j_ < 2; ++j_) {                    \
      bfr[(nh) * 2 + j_][0] = *(const bf16x8*)(p_ + j_ * 16 * 64 + off0); \
      bfr[(nh) * 2 + j_][1] = *(const bf16x8*)(p_ + j_ * 16 * 64 + off1); \
    }                                                                     \
  } while (0)

#define MFMA_QUAD(mh, nh)                                                   \
  _Pragma("unroll") for (int kk_ = 0; kk_ < 2; ++kk_)                       \
  _Pragma("unroll") for (int i_ = 0; i_ < 4; ++i_)                          \
  _Pragma("unroll") for (int j_ = 0; j_ < 2; ++j_)                          \
    acc[(mh) * 4 + i_][(nh) * 2 + j_] =                                     \
        __builtin_amdgcn_mfma_f32_16x16x32_bf16(                            \
            af[i_][kk_], bfr[(nh) * 2 + j_][kk_],                           \
            acc[(mh) * 4 + i_][(nh) * 2 + j_], 0, 0, 0)

#define PHASE_TAIL(mh, nh)                                 \
  do {                                                     \
    __builtin_amdgcn_s_barrier();                          \
    asm volatile("s_waitcnt lgkmcnt(0)" ::: "memory");     \
    __builtin_amdgcn_s_setprio(1);                         \
    MFMA_QUAD(mh, nh);                                     \
    __builtin_amdgcn_s_setprio(0);                         \
    __builtin_amdgcn_s_barrier();                          \
  } while (0)

#define PHASE_TAIL_VM(mh, nh, vmstr)                       \
  do {                                                     \
    __builtin_amdgcn_s_barrier();                          \
    asm volatile("s_waitcnt lgkmcnt(0)" ::: "memory");     \
    __builtin_amdgcn_s_setprio(1);                         \
    MFMA_QUAD(mh, nh);                                     \
    __builtin_amdgcn_s_setprio(0);                         \
    asm volatile("s_waitcnt " vmstr ::: "memory");         \
    __builtin_amdgcn_s_barrier();                          \
  } while (0)

__global__ __launch_bounds__(512, 2) void gemm_kernel(const u16* __restrict__ A,
                                                      const u16* __restrict__ B,
                                                      float* __restrict__ C) {
  __shared__ __align__(16) u16 sh[2][2][BM * BK];  // 128 KiB

  int tid = threadIdx.x;
  int lane = tid & 63, wave = tid >> 6;
  int wm = wave >> 2, wn = wave & 3;  // 2 x 4 wave grid, 128x64 out per wave

  // XCD-aware swizzle: 512 wgs, 512 % 8 == 0 -> simple form is bijective.
  int bid = blockIdx.y * gridDim.x + blockIdx.x;
  int swz = (bid & 7) * 64 + (bid >> 3);
  int bm = swz >> 4, bn = swz & 15;

  // Staging: chunk i covers rows i*64..i*64+63; linear LDS dest, source
  // granule pre-swizzled by row&7 so fragment reads un-swizzle.
  int srow = tid >> 3;
  int sg = (tid & 7) ^ (srow & 7);
  const u16* gA = A + (size_t)(bm * BM + srow) * K_TOT + sg * 8;
  const u16* gB = B + (size_t)(bn * BN + srow) * K_TOT + sg * 8;

  // Fragment addressing: lane = q*16+m holds k=8q..8q+8 of row m; granule g
  // stored at g^(row&7), row&7 == m&7.
  int m = lane & 15, q = lane >> 4;
  int x7 = m & 7;
  int off0 = (q ^ x7) << 3;
  int off1 = ((q + 4) ^ x7) << 3;

  f32x4 acc[8][4] = {};
  bf16x8 af[4][2], bfr[4][2];

  // Prologue: tile0 fully into buf0 (8), tile1's A0+B into buf1 (6).
  // Tile1's A1 chunks are staged by iter0.p0 (steady-state slot).
#pragma unroll
  for (int i = 0; i < 4; ++i) STAGE_A(0, 0, i);
#pragma unroll
  for (int i = 0; i < 4; ++i) STAGE_B(0, 0, i);
  STAGE_A(1, BK, 0);
  STAGE_A(1, BK, 2);
#pragma unroll
  for (int i = 0; i < 4; ++i) STAGE_B(1, BK, i);
  asm volatile("s_waitcnt vmcnt(6)" ::: "memory");  // tile0 landed
  __builtin_amdgcn_s_barrier();

  for (int J = 0; J < NT / 2 - 1; ++J) {
    int k1 = (2 * J + 1) * BK;  // tile 2J+1 (buf1)
    int k2 = k1 + BK;           // tile 2J+2 (buf0)
    int k3 = k2 + BK;           // tile 2J+3 (buf1)
    {  // ---- tile 2J from buf0, phases 0-3 ----
      const u16* sA = sh[0][0];
      const u16* sB = sh[0][1];
      // p0: read A0+B0 (12); stage A1 chunks of tile 2J+1 -> buf1
      LOAD_A(0);
      LOAD_B(0);
      STAGE_A(1, k1, 1);
      STAGE_A(1, k1, 3);
      asm volatile("s_waitcnt lgkmcnt(8)" ::: "memory");
      PHASE_TAIL(0, 0);
      // p1: read B1 (4); stage A0 chunks of tile 2J+2 -> buf0
      LOAD_B(1);
      STAGE_A(0, k2, 0);
      STAGE_A(0, k2, 2);
      PHASE_TAIL(0, 1);
      // p2: read A1 (8); stage B chunks 0,1 of tile 2J+2
      LOAD_A(1);
      STAGE_B(0, k2, 0);
      STAGE_B(0, k2, 1);
      PHASE_TAIL(1, 1);
      // p3: pure MFMA; stage B chunks 2,3 of tile 2J+2;
      // vmcnt(6) drains tile 2J+1 fully (keeps p1-p3's 6 in flight).
      STAGE_B(0, k2, 2);
      STAGE_B(0, k2, 3);
      PHASE_TAIL_VM(1, 0, "vmcnt(6)");
    }
    {  // ---- tile 2J+1 from buf1, phases 4-7 ----
      const u16* sA = sh[1][0];
      const u16* sB = sh[1][1];
      // p4: read A0+B0; stage A1 chunks of tile 2J+2 -> buf0
      LOAD_A(0);
      LOAD_B(0);
      STAGE_A(0, k2, 1);
      STAGE_A(0, k2, 3);
      asm volatile("s_waitcnt lgkmcnt(8)" ::: "memory");
      PHASE_TAIL(0, 0);
      // p5: read B1; stage A0 chunks of tile 2J+3 -> buf1
      LOAD_B(1);
      STAGE_A(1, k3, 0);
      STAGE_A(1, k3, 2);
      PHASE_TAIL(0, 1);
      // p6: read A1; stage B chunks 0,1 of tile 2J+3
      LOAD_A(1);
      STAGE_B(1, k3, 0);
      STAGE_B(1, k3, 1);
      PHASE_TAIL(1, 1);
      // p7: pure MFMA; stage B chunks 2,3 of tile 2J+3;
      // vmcnt(6) drains tile 2J+2 fully.
      STAGE_B(1, k3, 2);
      STAGE_B(1, k3, 3);
      PHASE_TAIL_VM(1, 0, "vmcnt(6)");
    }
  }

  // Epilogue: tiles 62 (buf0) and 63 (buf1).
  {
    const u16* sA = sh[0][0];
    const u16* sB = sh[0][1];
    // ep.p0: stage A1 chunks of tile 63 (its A0+B staged in last loop iter)
    LOAD_A(0);
    LOAD_B(0);
    STAGE_A(1, (NT - 1) * BK, 1);
    STAGE_A(1, (NT - 1) * BK, 3);
    asm volatile("s_waitcnt lgkmcnt(8)" ::: "memory");
    PHASE_TAIL(0, 0);
    LOAD_B(1);
    PHASE_TAIL(0, 1);
    LOAD_A(1);
    PHASE_TAIL(1, 1);
    PHASE_TAIL_VM(1, 0, "vmcnt(0)");  // tile 63 fully landed
  }
  {
    const u16* sA = sh[1][0];
    const u16* sB = sh[1][1];
    LOAD_A(0);
    LOAD_B(0);
    asm volatile("s_waitcnt lgkmcnt(8)" ::: "memory");
    PHASE_TAIL(0, 0);
    LOAD_B(1);
    PHASE_TAIL(0, 1);
    LOAD_A(1);
    PHASE_TAIL(1, 1);
    PHASE_TAIL(1, 0);
  }

  // C/D layout: col = lane&15, row = (lane>>4)*4 + reg
  int r0 = bm * BM + wm * 128 + (q << 2);
  int c0 = bn * BN + wn * 64 + m;
#pragma unroll
  for (int i = 0; i < 8; ++i)
#pragma unroll
    for (int j = 0; j < 4; ++j)
#pragma unroll
      for (int p = 0; p < 4; ++p)
        C[(size_t)(r0 + i * 16 + p) * N_TOT + (c0 + j * 16)] = acc[i][j][p];
}

extern "C" void kernel_launch(void* const* d_in, const int* in_sizes, int n_in,
                              void* d_out, int out_size, void* d_ws, size_t ws_size,
                              hipStream_t stream) {
  const float* x = (const float*)d_in[0];       // [4,2048,4096] fp32
  const int* wq = (const int*)d_in[1];          // [4096,4096] int32
  const float* scales = (const float*)d_in[2];  // [4096,64] fp32
  const float* Aw = (const float*)d_in[3];      // [16,4096] fp32
  const float* Bw = (const float*)d_in[4];      // [4096,16] fp32
  float* out = (float*)d_out;                   // [8192,4096] fp32

  u16* xb = (u16*)d_ws;                                       // 67,108,864 B
  u16* Wb = (u16*)((char*)d_ws + (size_t)M_TOT * K_TOT * 2);  // 33,554,432 B

  prep_kernel<<<DQ_BLOCKS + CVT_BLOCKS, 256, 0, stream>>>(
      x, xb, wq, scales, Aw, Bw, Wb);
  gemm_kernel<<<dim3(N_TOT / BN, M_TOT / BM), 512, 0, stream>>>(xb, Wb, out);
}

// Round 4
// 482.411 us; speedup vs baseline: 1.2474x; 1.0030x over previous
//
#include <hip/hip_runtime.h>

typedef unsigned int u32;
typedef unsigned short u16;
typedef __bf16 bf16x8 __attribute__((ext_vector_type(8)));
typedef float f32x4 __attribute__((ext_vector_type(4)));

#define M_TOT 8192
#define N_TOT 4096
#define K_TOT 4096
#define RANK 16

#define BM 256
#define BN 256
#define BK 64
#define NT (K_TOT / BK)

#define DQ_BLOCKS 1024    // (K_TOT/1024)*(N_TOT/16)
#define CVT_BLOCKS 16384  // (M_TOT*K_TOT)/(256*8)

__constant__ float NF4_TAB[16] = {
    -1.0f, -0.6961928009986877f, -0.5250730514526367f, -0.39491748809814453f,
    -0.28444138169288635f, -0.18477343022823334f, -0.09105003625154495f, 0.0f,
    0.07958029955625534f, 0.16093020141124725f, 0.24611230194568634f,
    0.33791524171829224f, 0.44070982933044434f, 0.5626170039176941f,
    0.7229568362236023f, 1.0f};

__device__ __forceinline__ u16 f2bf(float f) {
  u32 u = __builtin_bit_cast(u32, f);
  return (u16)((u + 0x7FFFu + ((u >> 16) & 1u)) >> 16);  // RNE
}

__device__ __forceinline__ void async_copy16(const u16* g, u16* l) {
  __builtin_amdgcn_global_load_lds(
      (const __attribute__((address_space(1))) u32*)g,
      (__attribute__((address_space(3))) u32*)l, 16, 0, 0);
}

// ---------------- fused prep: NF4 dequant + LoRA fold FIRST, then cvt ----
__global__ __launch_bounds__(256) void prep_kernel(
    const float* __restrict__ x, u16* __restrict__ xb,
    const int* __restrict__ wq, const float* __restrict__ scales,
    const float* __restrict__ Aw, const float* __restrict__ Bw,
    u16* __restrict__ Wb) {
  if (blockIdx.x >= DQ_BLOCKS) {
    int t = (blockIdx.x - DQ_BLOCKS) * 256 + threadIdx.x;
    const float4* xv = (const float4*)x;
    float4 v0 = xv[2 * t], v1 = xv[2 * t + 1];
    uint4 o;
    o.x = (u32)f2bf(v0.x) | ((u32)f2bf(v0.y) << 16);
    o.y = (u32)f2bf(v0.z) | ((u32)f2bf(v0.w) << 16);
    o.z = (u32)f2bf(v1.x) | ((u32)f2bf(v1.y) << 16);
    o.w = (u32)f2bf(v1.z) | ((u32)f2bf(v1.w) << 16);
    ((uint4*)xb)[t] = o;
    return;
  }
  int bx = blockIdx.x & 3, by = blockIdx.x >> 2;

  __shared__ float Bs[16 * RANK];
  int t = threadIdx.x;
  int o0 = by * 16;
  int tabi = __builtin_bit_cast(int, NF4_TAB[t & 15]);
  Bs[t] = Bw[o0 * RANK + t];
  __syncthreads();

  int i0 = bx * 1024 + t * 4;
  float a[RANK][4];
#pragma unroll
  for (int r = 0; r < RANK; ++r) {
    float4 v = *(const float4*)(Aw + r * K_TOT + i0);
    a[r][0] = v.x; a[r][1] = v.y; a[r][2] = v.z; a[r][3] = v.w;
  }
#pragma unroll
  for (int j = 0; j < 16; ++j) {
    int o = o0 + j;
    int4 q = *(const int4*)(wq + (size_t)o * K_TOT + i0);
    float s = scales[o * (K_TOT / 64) + (i0 >> 6)];
    float d0 = 0.f, d1 = 0.f, d2 = 0.f, d3 = 0.f;
#pragma unroll
    for (int r = 0; r < RANK; ++r) {
      float b = Bs[j * RANK + r];
      d0 += b * a[r][0]; d1 += b * a[r][1];
      d2 += b * a[r][2]; d3 += b * a[r][3];
    }
    float t0 = __builtin_bit_cast(float, __builtin_amdgcn_ds_bpermute((q.x & 15) << 2, tabi));
    float t1 = __builtin_bit_cast(float, __builtin_amdgcn_ds_bpermute((q.y & 15) << 2, tabi));
    float t2 = __builtin_bit_cast(float, __builtin_amdgcn_ds_bpermute((q.z & 15) << 2, tabi));
    float t3 = __builtin_bit_cast(float, __builtin_amdgcn_ds_bpermute((q.w & 15) << 2, tabi));
    float w0 = t0 * s + 2.0f * d0;
    float w1 = t1 * s + 2.0f * d1;
    float w2 = t2 * s + 2.0f * d2;
    float w3 = t3 * s + 2.0f * d3;
    uint2 ov;
    ov.x = (u32)f2bf(w0) | ((u32)f2bf(w1) << 16);
    ov.y = (u32)f2bf(w2) | ((u32)f2bf(w3) << 16);
    *(uint2*)(Wb + (size_t)o * K_TOT + i0) = ov;
  }
}

// ---------------- bf16 GEMM: C[M,N] = A[M,K] * B[N,K]^T ----------------
// 8-phase ring, balanced reads 8/4/8/4 (m201-matched): p3 pre-reads the NEXT
// tile's first A-half (af[0..1]) in its post-MFMA shadow, legal because p3's
// vmcnt(6) proves the next tile's buffer is fully landed. p0 then reads only
// af[2..3]+B0. Counted vmcnt only at p3/p7, never 0 in the main loop.
#define STAGE_A(buf, k0, i) \
  async_copy16(gA + (size_t)(i) * 64 * K_TOT + (k0), &sh[buf][0][(i) * 4096 + tid * 8])
#define STAGE_B(buf, k0, i) \
  async_copy16(gB + (size_t)(i) * 64 * K_TOT + (k0), &sh[buf][1][(i) * 4096 + tid * 8])

#define PRELOAD_A0(bufi)                                  \
  do {                                                    \
    const u16* pn_ = sh[bufi][0] + (wm * 128 + m) * 64;   \
    af[0][0] = *(const bf16x8*)(pn_ + off0);              \
    af[0][1] = *(const bf16x8*)(pn_ + off1);              \
    af[1][0] = *(const bf16x8*)(pn_ + 16 * 64 + off0);    \
    af[1][1] = *(const bf16x8*)(pn_ + 16 * 64 + off1);    \
  } while (0)

#define LOAD_A0_REST                                          \
  do {                                                        \
    const u16* p_ = sA + (wm * 128 + m) * 64;                 \
    af[2][0] = *(const bf16x8*)(p_ + 2 * 16 * 64 + off0);     \
    af[2][1] = *(const bf16x8*)(p_ + 2 * 16 * 64 + off1);     \
    af[3][0] = *(const bf16x8*)(p_ + 3 * 16 * 64 + off0);     \
    af[3][1] = *(const bf16x8*)(p_ + 3 * 16 * 64 + off1);     \
  } while (0)

#define LOAD_A(mh)                                              \
  do {                                                          \
    const u16* p_ = sA + (wm * 128 + (mh) * 64 + m) * 64;       \
    _Pragma("unroll") for (int i_ = 0; i_ < 4; ++i_) {          \
      af[i_][0] = *(const bf16x8*)(p_ + i_ * 16 * 64 + off0);   \
      af[i_][1] = *(const bf16x8*)(p_ + i_ * 16 * 64 + off1);   \
    }                                                           \
  } while (0)

#define LOAD_B(nh)                                                        \
  do {                                                                    \
    const u16* p_ = sB + (wn * 64 + (nh) * 32 + m) * 64;                  \
    _Pragma("unroll") for (int j_ = 0; j_ < 2; ++j_) {                    \
      bfr[(nh) * 2 + j_][0] = *(const bf16x8*)(p_ + j_ * 16 * 64 + off0); \
      bfr[(nh) * 2 + j_][1] = *(const bf16x8*)(p_ + j_ * 16 * 64 + off1); \
    }                                                                     \
  } while (0)

#define MFMA_QUAD(mh, nh)                                                   \
  _Pragma("unroll") for (int kk_ = 0; kk_ < 2; ++kk_)                       \
  _Pragma("unroll") for (int i_ = 0; i_ < 4; ++i_)                          \
  _Pragma("unroll") for (int j_ = 0; j_ < 2; ++j_)                          \
    acc[(mh) * 4 + i_][(nh) * 2 + j_] =                                     \
        __builtin_amdgcn_mfma_f32_16x16x32_bf16(                            \
            af[i_][kk_], bfr[(nh) * 2 + j_][kk_],                           \
            acc[(mh) * 4 + i_][(nh) * 2 + j_], 0, 0, 0)

#define PHASE_TAIL(mh, nh)                                 \
  do {                                                     \
    __builtin_amdgcn_s_barrier();                          \
    asm volatile("s_waitcnt lgkmcnt(0)" ::: "memory");     \
    __builtin_amdgcn_s_setprio(1);                         \
    MFMA_QUAD(mh, nh);                                     \
    __builtin_amdgcn_s_setprio(0);                         \
    __builtin_amdgcn_s_barrier();                          \
  } while (0)

// p3/p7 variant: counted vmcnt after MFMA, then pre-read next tile's A0 half
// (buffer proven complete by the vmcnt) in the barrier shadow.
#define PHASE_TAIL_VM_PRE(mh, nh, vmstr, bufi)             \
  do {                                                     \
    __builtin_amdgcn_s_barrier();                          \
    asm volatile("s_waitcnt lgkmcnt(0)" ::: "memory");     \
    __builtin_amdgcn_s_setprio(1);                         \
    MFMA_QUAD(mh, nh);                                     \
    __builtin_amdgcn_s_setprio(0);                         \
    asm volatile("s_waitcnt " vmstr ::: "memory");         \
    PRELOAD_A0(bufi);                                      \
    __builtin_amdgcn_s_barrier();                          \
  } while (0)

__global__ __launch_bounds__(512, 2) void gemm_kernel(const u16* __restrict__ A,
                                                      const u16* __restrict__ B,
                                                      float* __restrict__ C) {
  __shared__ __align__(16) u16 sh[2][2][BM * BK];  // 128 KiB

  int tid = threadIdx.x;
  int lane = tid & 63, wave = tid >> 6;
  int wm = wave >> 2, wn = wave & 3;  // 2 x 4 wave grid, 128x64 out per wave

  // XCD-aware swizzle: 512 wgs, 512 % 8 == 0 -> simple form is bijective.
  int bid = blockIdx.y * gridDim.x + blockIdx.x;
  int swz = (bid & 7) * 64 + (bid >> 3);
  int bm = swz >> 4, bn = swz & 15;

  // Staging: chunk i covers rows i*64..i*64+63; linear LDS dest, source
  // granule pre-swizzled by row&7 so fragment reads un-swizzle.
  int srow = tid >> 3;
  int sg = (tid & 7) ^ (srow & 7);
  const u16* gA = A + (size_t)(bm * BM + srow) * K_TOT + sg * 8;
  const u16* gB = B + (size_t)(bn * BN + srow) * K_TOT + sg * 8;

  // Fragment addressing: lane = q*16+m holds k=8q..8q+8 of row m; granule g
  // stored at g^(row&7), row&7 == m&7.
  int m = lane & 15, q = lane >> 4;
  int x7 = m & 7;
  int off0 = (q ^ x7) << 3;
  int off1 = ((q + 4) ^ x7) << 3;

  f32x4 acc[8][4] = {};
  bf16x8 af[4][2], bfr[4][2];

  // Prologue: tile0 fully into buf0 (8), tile1's A0+B into buf1 (6).
#pragma unroll
  for (int i = 0; i < 4; ++i) STAGE_A(0, 0, i);
#pragma unroll
  for (int i = 0; i < 4; ++i) STAGE_B(0, 0, i);
  STAGE_A(1, BK, 0);
  STAGE_A(1, BK, 2);
#pragma unroll
  for (int i = 0; i < 4; ++i) STAGE_B(1, BK, i);
  asm volatile("s_waitcnt vmcnt(6)" ::: "memory");  // tile0 landed
  PRELOAD_A0(0);                                    // tile0 af[0..1]
  __builtin_amdgcn_s_barrier();

  for (int J = 0; J < NT / 2 - 1; ++J) {
    int k1 = (2 * J + 1) * BK;  // tile 2J+1 (buf1)
    int k2 = k1 + BK;           // tile 2J+2 (buf0)
    int k3 = k2 + BK;           // tile 2J+3 (buf1)
    {  // ---- tile 2J from buf0, phases 0-3 ----
      const u16* sA = sh[0][0];
      const u16* sB = sh[0][1];
      // p0: read af[2..3]+B0 (8); stage A1 chunks of tile 2J+1 -> buf1
      LOAD_A0_REST;
      LOAD_B(0);
      STAGE_A(1, k1, 1);
      STAGE_A(1, k1, 3);
      PHASE_TAIL(0, 0);
      // p1: read B1 (4); stage A0 chunks of tile 2J+2 -> buf0
      LOAD_B(1);
      STAGE_A(0, k2, 0);
      STAGE_A(0, k2, 2);
      PHASE_TAIL(0, 1);
      // p2: read A1 (8); stage B chunks 0,1 of tile 2J+2
      LOAD_A(1);
      STAGE_B(0, k2, 0);
      STAGE_B(0, k2, 1);
      PHASE_TAIL(1, 1);
      // p3: MFMA; stage B chunks 2,3 of tile 2J+2; vmcnt(6) drains tile
      // 2J+1 fully; pre-read its af[0..1] from buf1 in the barrier shadow.
      STAGE_B(0, k2, 2);
      STAGE_B(0, k2, 3);
      PHASE_TAIL_VM_PRE(1, 0, "vmcnt(6)", 1);
    }
    {  // ---- tile 2J+1 from buf1, phases 4-7 ----
      const u16* sA = sh[1][0];
      const u16* sB = sh[1][1];
      // p4: read af[2..3]+B0; stage A1 chunks of tile 2J+2 -> buf0
      LOAD_A0_REST;
      LOAD_B(0);
      STAGE_A(0, k2, 1);
      STAGE_A(0, k2, 3);
      PHASE_TAIL(0, 0);
      // p5: read B1; stage A0 chunks of tile 2J+3 -> buf1
      LOAD_B(1);
      STAGE_A(1, k3, 0);
      STAGE_A(1, k3, 2);
      PHASE_TAIL(0, 1);
      // p6: read A1; stage B chunks 0,1 of tile 2J+3
      LOAD_A(1);
      STAGE_B(1, k3, 0);
      STAGE_B(1, k3, 1);
      PHASE_TAIL(1, 1);
      // p7: MFMA; stage B chunks 2,3 of tile 2J+3; vmcnt(6) drains tile
      // 2J+2; pre-read its af[0..1] from buf0.
      STAGE_B(1, k3, 2);
      STAGE_B(1, k3, 3);
      PHASE_TAIL_VM_PRE(1, 0, "vmcnt(6)", 0);
    }
  }

  // Epilogue: tiles 62 (buf0) and 63 (buf1). af[0..1] of tile 62 pre-read
  // by the last loop iteration's p7.
  {
    const u16* sA = sh[0][0];
    const u16* sB = sh[0][1];
    LOAD_A0_REST;
    LOAD_B(0);
    STAGE_A(1, (NT - 1) * BK, 1);
    STAGE_A(1, (NT - 1) * BK, 3);
    PHASE_TAIL(0, 0);
    LOAD_B(1);
    PHASE_TAIL(0, 1);
    LOAD_A(1);
    PHASE_TAIL(1, 1);
    PHASE_TAIL_VM_PRE(1, 0, "vmcnt(0)", 1);  // tile 63 landed; pre-read af01
  }
  {
    const u16* sA = sh[1][0];
    const u16* sB = sh[1][1];
    LOAD_A0_REST;
    LOAD_B(0);
    PHASE_TAIL(0, 0);
    LOAD_B(1);
    PHASE_TAIL(0, 1);
    LOAD_A(1);
    PHASE_TAIL(1, 1);
    PHASE_TAIL(1, 0);
  }

  // C/D layout: col = lane&15, row = (lane>>4)*4 + reg
  int r0 = bm * BM + wm * 128 + (q << 2);
  int c0 = bn * BN + wn * 64 + m;
#pragma unroll
  for (int i = 0; i < 8; ++i)
#pragma unroll
    for (int j = 0; j < 4; ++j)
#pragma unroll
      for (int p = 0; p < 4; ++p)
        C[(size_t)(r0 + i * 16 + p) * N_TOT + (c0 + j * 16)] = acc[i][j][p];
}

extern "C" void kernel_launch(void* const* d_in, const int* in_sizes, int n_in,
                              void* d_out, int out_size, void* d_ws, size_t ws_size,
                              hipStream_t stream) {
  const float* x = (const float*)d_in[0];       // [4,2048,4096] fp32
  const int* wq = (const int*)d_in[1];          // [4096,4096] int32
  const float* scales = (const float*)d_in[2];  // [4096,64] fp32
  const float* Aw = (const float*)d_in[3];      // [16,4096] fp32
  const float* Bw = (const float*)d_in[4];      // [4096,16] fp32
  float* out = (float*)d_out;                   // [8192,4096] fp32

  u16* xb = (u16*)d_ws;                                       // 67,108,864 B
  u16* Wb = (u16*)((char*)d_ws + (size_t)M_TOT * K_TOT * 2);  // 33,554,432 B

  prep_kernel<<<DQ_BLOCKS + CVT_BLOCKS, 256, 0, stream>>>(
      x, xb, wq, scales, Aw, Bw, Wb);
  gemm_kernel<<<dim3(N_TOT / BN, M_TOT / BM), 512, 0, stream>>>(xb, Wb, out);
}